// Round 2
// baseline (131.395 us; speedup 1.0000x reference)
//
#include <hip/hip_runtime.h>

// FeatureAlign on MI355X.
// Shapes: N=4, D=256, H=W=64, fp32 in/out.
// Key insight: only 12 neighbor offsets of the affinity matrix are ever used:
//   o0..o8  : 3x3 window (dy,dx in {-1,0,1})   -> mass
//   o0,o9..11: {(-1,-1),(-1,2),(2,-1),(2,2)}   -> agg weights
// pn^2 at each neighbor is accumulated for free from the same prev loads.

#define HH 64
#define WW 64
#define DD 256
#define HWD (HH * WW)

__global__ __launch_bounds__(512)
void FeatureAlign_64063732187249_kernel(const float* __restrict__ cur,
                                        const float* __restrict__ prev,
                                        const float* __restrict__ mem,
                                        float* __restrict__ out)
{
    const int x  = threadIdx.x;   // 0..63 : column (coalesced)
    const int tz = threadIdx.y;   // 0..7  : d-split group
    const int r  = blockIdx.x;    // 0..63 : row
    const int n  = blockIdx.y;    // 0..3  : batch

    const size_t noff = (size_t)n * DD * HWD;
    const float* __restrict__ cur_n  = cur  + noff;
    const float* __restrict__ prev_n = prev + noff;
    const float* __restrict__ mem_n  = mem  + noff;
    float* __restrict__ out_n        = out  + noff;

    // 12 offsets: 0..8 = 3x3 window (row-major), 9..11 = extra agg offsets.
    const int ody[12] = {-1,-1,-1, 0,0,0, 1,1,1, -1, 2, 2};
    const int odx[12] = {-1, 0, 1,-1,0,1,-1,0,1,  2,-1, 2};

    int pidx[12];
    #pragma unroll
    for (int o = 0; o < 12; ++o) {
        int py = r + ody[o]; py = min(max(py, 0), HH - 1);
        int px = x + odx[o]; px = min(max(px, 0), WW - 1);
        pidx[o] = py * WW + px;
    }
    const int q = r * WW + x;

    // acc[0..11]=dot_o, acc[12..23]=pn^2_o, acc[24]=cn^2
    float acc[25];
    #pragma unroll
    for (int a = 0; a < 25; ++a) acc[a] = 0.f;

    const int d0 = tz * (DD / 8);   // 32 channels per thread

    #pragma unroll 4
    for (int k = 0; k < DD / 8; ++k) {
        const int d = d0 + k;
        const float* __restrict__ cd = cur_n  + (size_t)d * HWD;
        const float* __restrict__ pd = prev_n + (size_t)d * HWD;
        const float c = cd[q];
        acc[24] = fmaf(c, c, acc[24]);
        #pragma unroll
        for (int o = 0; o < 12; ++o) {
            const float v = pd[pidx[o]];
            acc[o]      = fmaf(c, v, acc[o]);
            acc[12 + o] = fmaf(v, v, acc[12 + o]);
        }
    }

    __shared__ float red[25][8][64];   // 51.2 KB
    __shared__ float tot[25][64];      //  6.4 KB
    __shared__ float wres[5][64];      //  1.3 KB

    #pragma unroll
    for (int a = 0; a < 25; ++a) red[a][tz][x] = acc[a];
    __syncthreads();

    // reduce across the 8 d-groups; waves split the 25 accumulators
    for (int a = tz; a < 25; a += 8) {
        float s = 0.f;
        #pragma unroll
        for (int z = 0; z < 8; ++z) s += red[a][z][x];
        tot[a][x] = s;
    }
    __syncthreads();

    if (tz == 0) {
        const float cn = sqrtf(tot[24][x]) + 1e-8f;
        float aff[12];
        #pragma unroll
        for (int o = 0; o < 12; ++o) {
            const float pn = sqrtf(tot[12 + o][x]) + 1e-8f;
            aff[o] = fmaxf(tot[o][x] / (cn * pn), 0.f);
        }
        // mass: 3x3 window, zero-padded (skip out-of-bounds)
        float mass = 0.f;
        #pragma unroll
        for (int o = 0; o < 9; ++o) {
            const bool valid = (r + ody[o] >= 0) && (r + ody[o] < HH) &&
                               (x + odx[o] >= 0) && (x + odx[o] < WW);
            if (valid) mass += aff[o];
        }
        const bool  cond      = (mass > -10.f) && (mass < 10.f);
        const float mass_safe = (mass > 0.f) ? mass : 1.f;

        const int aggo[4] = {0, 9, 10, 11};
        #pragma unroll
        for (int j = 0; j < 4; ++j) {
            const int  o     = aggo[j];
            const bool valid = (r + ody[o] >= 0) && (r + ody[o] < HH) &&
                               (x + odx[o] >= 0) && (x + odx[o] < WW);
            const float a = aff[o];
            wres[j][x] = (valid && a > 0.f) ? (a / mass_safe) : 0.f;
        }
        wres[4][x] = cond ? 1.f : 0.f;
    }
    __syncthreads();

    const float w0 = wres[0][x], w1 = wres[1][x], w2 = wres[2][x], w3 = wres[3][x];
    const float cf = wres[4][x];
    const int p0 = pidx[0], p1 = pidx[9], p2 = pidx[10], p3 = pidx[11];

    #pragma unroll 4
    for (int k = 0; k < DD / 8; ++k) {
        const int d = d0 + k;
        const float* __restrict__ md = mem_n + (size_t)d * HWD;
        const float m   = md[q];
        const float agg = w0 * md[p0] + w1 * md[p1] + w2 * md[p2] + w3 * md[p3];
        const float res = m + ((d > 0) ? agg : 0.f);
        out_n[(size_t)d * HWD + q] = (cf != 0.f) ? res : 0.f;
    }
}

extern "C" void kernel_launch(void* const* d_in, const int* in_sizes, int n_in,
                              void* d_out, int out_size, void* d_ws, size_t ws_size,
                              hipStream_t stream)
{
    const float* cur  = (const float*)d_in[0];
    const float* prev = (const float*)d_in[1];
    const float* mem  = (const float*)d_in[2];
    float* out        = (float*)d_out;

    dim3 block(64, 8, 1);   // 64 cols x 8 d-groups = 512 threads (8 waves)
    dim3 grid(HH, 4, 1);    // one block per (row, batch): 256 blocks

    hipLaunchKernelGGL(FeatureAlign_64063732187249_kernel, grid, block, 0, stream,
                       cur, prev, mem, out);
}